// Round 7
// baseline (259.922 us; speedup 1.0000x reference)
//
#include <hip/hip_runtime.h>
#include <hip/hip_bf16.h>

#define DB 8
#define DN 1024
#define DP 1024
#define DC 256
#define DNS 32
#define DBP (DB * DP)
#define K1 288   // padded GEMM1 K (256 feats + 3 gx + 29 zeros)
#define K2 256
#define XS 296   // x_lds row stride in bf16 elems (592 B; 148 dwords == 20 mod 32)
#define YS 258   // epilogue y-tile row stride in bf16 (129 dwords == 1 mod 32)
#define ROWS 128 // 4 bp per block (round-5 best config)
#define NG (DBP / 4)
#define NK1 (K1 / 32)  // 9
#define NK2 (K2 / 32)  // 8

constexpr float kRadius = 0.05f;
constexpr float kR2 = kRadius * kRadius;
constexpr float kHmin = -0.02f;
constexpr float kHmax = 0.04f;
constexpr float kEps = 1e-5f;
constexpr float kInvCnt = 1.0f / (float)(DB * DP * DNS);

typedef __bf16 bf16x8 __attribute__((ext_vector_type(8)));
typedef float f32x4 __attribute__((ext_vector_type(4)));
static_assert(sizeof(bf16x8) == 16, "bf16x8 must be 16B");

// ---- workspace layout (in floats) ----
constexpr size_t OF_FEATST = 0;                                   // B*N*C bf16
constexpr size_t OF_W1B  = OF_FEATST + (size_t)DB * DN * DC / 2;  // DC*K1 bf16
constexpr size_t OF_W2B  = OF_W1B + (size_t)DC * K1 / 2;          // DC*K2 bf16
constexpr size_t OF_IDX  = OF_W2B + (size_t)DC * K2 / 2;          // BP*NS int32
constexpr size_t OF_GX   = OF_IDX + (size_t)DBP * DNS;            // BP*NS*3
constexpr size_t OF_PART = OF_GX + (size_t)DBP * DNS * 3;         // NG*C*2
constexpr size_t OF_YMAX = OF_PART + (size_t)DBP * DC * 2;        // BP*C
constexpr size_t OF_YMIN = OF_YMAX + (size_t)DBP * DC;            // BP*C
constexpr size_t OF_BN1  = OF_YMIN + (size_t)DBP * DC;            // 512
constexpr size_t OF_BN2  = OF_BN1 + 512;                          // 512
// ---- stats-via-counts scratch ----
constexpr size_t OF_CNT  = OF_BN2 + 512;                          // B*N
constexpr size_t OF_GW   = OF_CNT + (size_t)DB * DN;              // B*3*N
constexpr size_t OF_GG   = OF_GW + (size_t)DB * 3 * DN;           // 16 (use 9)
constexpr size_t OF_CM   = OF_GG + 16;                            // 257*259
constexpr int    ZN      = DB * DN + DB * 3 * DN + 16 + 257 * 259;

__device__ inline ushort f2b(float x) {
  union { __hip_bfloat16 h; ushort u; } c;
  c.h = __float2bfloat16(x);
  return c.u;
}
__device__ inline float b2f(ushort u) {
  union { uint u; float f; } c;
  c.u = (uint)u << 16;
  return c.f;
}

// ---------------------------------------------------------------------------
// feats (B,C,N) f32 -> featsTb (B,N,C) bf16 via LDS tile transpose
__global__ void k_transpose_feats(const float* __restrict__ f, uint* __restrict__ ftb) {
  __shared__ float t[32][33];
  int ct = blockIdx.x, nt = blockIdx.y, b = blockIdx.z;
  int tx = threadIdx.x, ty = threadIdx.y;  // 32 x 8
#pragma unroll
  for (int k = 0; k < 4; ++k) {
    int c = ct * 32 + ty + k * 8;
    t[ty + k * 8][tx] = f[((size_t)b * DC + c) * DN + nt * 32 + tx];
  }
  __syncthreads();
  int tid = ty * 32 + tx;
  uint* dst = ftb + (size_t)b * DN * (DC / 2);
#pragma unroll
  for (int it = 0; it < 2; ++it) {
    int idx = it * 256 + tid;
    int nl = idx >> 4, cp = idx & 15;
    uint v = (uint)f2b(t[2 * cp][nl]) | ((uint)f2b(t[2 * cp + 1][nl]) << 16);
    dst[(size_t)(nt * 32 + nl) * (DC / 2) + ct * 16 + cp] = v;
  }
}

// W1 (256,259) f32 -> W1b (256,K1) bf16, K permuted: k'=0..255 <- k=3..258,
// k'=256..258 <- k=0..2 (gx), rest zero
__global__ void k_prep_w1(const float* __restrict__ W1, ushort* __restrict__ W1b) {
  int gid = blockIdx.x * 256 + threadIdx.x;
  if (gid >= DC * K1) return;
  int o = gid / K1, kp = gid - o * K1;
  float v = 0.f;
  if (kp < 256) v = W1[o * 259 + 3 + kp];
  else if (kp < 259) v = W1[o * 259 + (kp - 256)];
  W1b[gid] = f2b(v);
}

__global__ void k_prep_w2(const float* __restrict__ W2, ushort* __restrict__ W2b) {
  int gid = blockIdx.x * 256 + threadIdx.x;
  if (gid >= DC * K2) return;
  W2b[gid] = f2b(W2[gid]);
}

// ---------------------------------------------------------------------------
// cylinder query + grouped/rotated xyz. One wave per (b,p).
__global__ void k_query(const float* __restrict__ xyz, const float* __restrict__ rot,
                        int* __restrict__ idxp, float* __restrict__ gxp) {
  int bp = blockIdx.x;
  int b = bp >> 10;
  int lane = threadIdx.x;
  __shared__ int sidx[DNS];
  __shared__ float srot[9], sc[3];
  if (lane < DNS) sidx[lane] = 0;
  if (lane < 9) srot[lane] = rot[(size_t)bp * 9 + lane];
  if (lane < 3) sc[lane] = xyz[(size_t)bp * 3 + lane];
  __syncthreads();
  float r00 = srot[0], r01 = srot[1], r02 = srot[2];
  float r10 = srot[3], r11 = srot[4], r12 = srot[5];
  float r20 = srot[6], r21 = srot[7], r22 = srot[8];
  float cx = sc[0], cy = sc[1], cz = sc[2];
  const float* xb = xyz + (size_t)b * DN * 3;
  int cnt = 0;
  for (int ch = 0; ch < DN / 64 && cnt < DNS; ++ch) {
    int n = ch * 64 + lane;
    float dx = xb[n * 3 + 0] - cx, dy = xb[n * 3 + 1] - cy, dz = xb[n * 3 + 2] - cz;
    float lx = dx * r00 + dy * r10 + dz * r20;
    float ly = dx * r01 + dy * r11 + dz * r21;
    float lz = dx * r02 + dy * r12 + dz * r22;
    bool m = (ly * ly + lz * lz < kR2) && (lx > kHmin) && (lx < kHmax);
    unsigned long long bal = __ballot(m);
    int rank = cnt + __popcll(bal & ((1ull << lane) - 1ull));
    if (m && rank < DNS) sidx[rank] = n;
    cnt += __popcll(bal);
  }
  __syncthreads();
  if (lane < DNS) {
    int j = sidx[lane];
    idxp[(size_t)bp * DNS + lane] = j;
    float gx = (xb[j * 3 + 0] - cx) / kRadius;
    float gy = (xb[j * 3 + 1] - cy) / kRadius;
    float gz = (xb[j * 3 + 2] - cz) / kRadius;
    float* gp = gxp + ((size_t)bp * DNS + lane) * 3;
    gp[0] = gx * r00 + gy * r10 + gz * r20;
    gp[1] = gx * r01 + gy * r11 + gz * r21;
    gp[2] = gx * r02 + gy * r12 + gz * r22;
  }
}

// ---------------------------------------------------------------------------
// zero scratch for the stats pipeline
__global__ void k_zero(float* __restrict__ p, int n) {
  int i = blockIdx.x * 256 + threadIdx.x;
  if (i < n) p[i] = 0.f;
}

// counts + weighted-gx sums per (b, point); gx*gx^T 3x3 global sum.
// 256 blocks x 256 threads x 4 samples each.
__global__ __launch_bounds__(256)
void k_count(const int* __restrict__ idxp, const float* __restrict__ gxp,
             float* __restrict__ cnt, float* __restrict__ gw, float* __restrict__ gg) {
  int t = threadIdx.x;
  float p[6] = {0.f, 0.f, 0.f, 0.f, 0.f, 0.f};
#pragma unroll
  for (int r = 0; r < 4; ++r) {
    int sid = blockIdx.x * 1024 + r * 256 + t;
    int b = sid >> 15;  // 32768 samples per batch
    int j = idxp[sid];
    const float* g = gxp + (size_t)sid * 3;
    float g0 = g[0], g1 = g[1], g2 = g[2];
    atomicAdd(&cnt[b * DN + j], 1.f);
    atomicAdd(&gw[(b * 3 + 0) * DN + j], g0);
    atomicAdd(&gw[(b * 3 + 1) * DN + j], g1);
    atomicAdd(&gw[(b * 3 + 2) * DN + j], g2);
    p[0] += g0 * g0; p[1] += g0 * g1; p[2] += g0 * g2;
    p[3] += g1 * g1; p[4] += g1 * g2; p[5] += g2 * g2;
  }
  __shared__ float sgg[4][6];
#pragma unroll
  for (int v = 0; v < 6; ++v) {
    float s = p[v];
#pragma unroll
    for (int m = 1; m < 64; m <<= 1) s += __shfl_xor(s, m, 64);
    if ((t & 63) == 0) sgg[t >> 6][v] = s;
  }
  __syncthreads();
  if (t < 6) {
    float s = sgg[0][t] + sgg[1][t] + sgg[2][t] + sgg[3][t];
    // symmetric fill: v -> (c,c') pairs
    const int i1[6] = {0, 1, 2, 4, 5, 8};  // (0,0)(0,1)(0,2)(1,1)(1,2)(2,2)
    const int i2[6] = {0, 3, 6, 4, 7, 8};
    atomicAdd(&gg[i1[t]], s);
    if (i2[t] != i1[t]) atomicAdd(&gg[i2[t]], s);
  }
}

// C(257x259) += F'(257x8192) * P^T : F' rows 0..255 = feats, 256 = ones;
// P cols: k2<256 -> feats*cnt, 256..258 -> gw. grid (5,5,32): z = batch*4 + nquarter.
__global__ __launch_bounds__(256)
void k_xxt(const float* __restrict__ feats, const float* __restrict__ cnt,
           const float* __restrict__ gw, float* __restrict__ Cm) {
  __shared__ float As[16][65], Bs[16][65];
  int bt = blockIdx.z >> 2;
  int n0 = (blockIdx.z & 3) * 256;
  int r0 = blockIdx.x * 64, c0 = blockIdx.y * 64;
  int tid = threadIdx.x;
  int ty = tid >> 4, tx = tid & 15;
  int li = tid >> 2, lq = tid & 3;
  const float* fb = feats + (size_t)bt * DC * DN;
  const float* cb = cnt + (size_t)bt * DN;
  const float* gb = gw + (size_t)bt * 3 * DN;
  float acc[4][4];
#pragma unroll
  for (int u = 0; u < 4; ++u)
#pragma unroll
    for (int v = 0; v < 4; ++v) acc[u][v] = 0.f;

  for (int nc = n0; nc < n0 + 256; nc += 16) {
    __syncthreads();
    {
      int k1 = r0 + li;
      float4 av = make_float4(0.f, 0.f, 0.f, 0.f);
      if (k1 < 256) av = *(const float4*)(fb + (size_t)k1 * DN + nc + lq * 4);
      else if (k1 == 256) av = make_float4(1.f, 1.f, 1.f, 1.f);
      As[lq * 4 + 0][li] = av.x; As[lq * 4 + 1][li] = av.y;
      As[lq * 4 + 2][li] = av.z; As[lq * 4 + 3][li] = av.w;
      int k2 = c0 + li;
      float4 bv = make_float4(0.f, 0.f, 0.f, 0.f);
      if (k2 < 256) {
        float4 f = *(const float4*)(fb + (size_t)k2 * DN + nc + lq * 4);
        float4 c4 = *(const float4*)(cb + nc + lq * 4);
        bv = make_float4(f.x * c4.x, f.y * c4.y, f.z * c4.z, f.w * c4.w);
      } else if (k2 < 259) {
        bv = *(const float4*)(gb + (size_t)(k2 - 256) * DN + nc + lq * 4);
      }
      Bs[lq * 4 + 0][li] = bv.x; Bs[lq * 4 + 1][li] = bv.y;
      Bs[lq * 4 + 2][li] = bv.z; Bs[lq * 4 + 3][li] = bv.w;
    }
    __syncthreads();
#pragma unroll
    for (int kk = 0; kk < 16; ++kk) {
      float a[4], bvv[4];
#pragma unroll
      for (int u = 0; u < 4; ++u) a[u] = As[kk][ty * 4 + u];
#pragma unroll
      for (int v = 0; v < 4; ++v) bvv[v] = Bs[kk][tx * 4 + v];
#pragma unroll
      for (int u = 0; u < 4; ++u)
#pragma unroll
        for (int v = 0; v < 4; ++v) acc[u][v] = fmaf(a[u], bvv[v], acc[u][v]);
    }
  }
#pragma unroll
  for (int u = 0; u < 4; ++u) {
    int k1 = r0 + ty * 4 + u;
    if (k1 > 256) continue;
#pragma unroll
    for (int v = 0; v < 4; ++v) {
      int k2 = c0 + tx * 4 + v;
      if (k2 < 259) atomicAdd(&Cm[(size_t)k1 * 259 + k2], acc[u][v]);
    }
  }
}

// per-channel bn1 scale/shift from C, gg: mu = w.sumx/N, Ey2 = w^T M w / N
__global__ __launch_bounds__(256)
void k_bn1(const float* __restrict__ Cm, const float* __restrict__ gg,
           const float* __restrict__ W1, const float* __restrict__ gam,
           const float* __restrict__ bet, float* __restrict__ bn) {
  int o = blockIdx.x, t = threadIdx.x;
  __shared__ float wv[259];
  __shared__ float rq[256], rs[256];
  for (int j = t; j < 259; j += 256)
    wv[j] = (j < 256) ? W1[o * 259 + 3 + j] : W1[o * 259 + (j - 256)];
  __syncthreads();
  float qp = 0.f, sp = 0.f;
  for (int j = t; j < 259; j += 256) {
    float u = 0.f;
    for (int i = 0; i < 256; ++i) u = fmaf(wv[i], Cm[(size_t)i * 259 + j], u);
#pragma unroll
    for (int c = 0; c < 3; ++c) {
      float m = (j < 256) ? Cm[(size_t)j * 259 + 256 + c] : gg[c * 3 + (j - 256)];
      u = fmaf(wv[256 + c], m, u);
    }
    qp = fmaf(wv[j], u, qp);
    sp = fmaf(wv[j], Cm[(size_t)256 * 259 + j], sp);
  }
  rq[t] = qp; rs[t] = sp;
  __syncthreads();
  for (int w = 128; w > 0; w >>= 1) {
    if (t < w) { rq[t] += rq[t + w]; rs[t] += rs[t + w]; }
    __syncthreads();
  }
  if (t == 0) {
    float mu = rs[0] * kInvCnt;
    float var = rq[0] * kInvCnt - mu * mu;
    var = var < 0.f ? 0.f : var;
    float sc = gam[o] * rsqrtf(var + kEps);
    bn[o] = sc;
    bn[DC + o] = bet[o] - mu * sc;
  }
}

// ---------------------------------------------------------------------------
// MFMA GEMM over 4 bp per block (128 sample rows), 16x16x32 bf16 — round-5 FULL.
// 256 threads = 4 waves; wave w owns o-range w*64 (4 o-tiles of 16), 8 s-tiles.
// D layout: col = lane&15 (=s), row = (lane>>4)*4 + reg (=o).
__global__ __launch_bounds__(256, 2)
void k_gemm_full(const uint4* __restrict__ ftb, const ushort* __restrict__ W1b,
                 const ushort* __restrict__ W2b, const int* __restrict__ idxp,
                 const float* __restrict__ gxp, const float* __restrict__ bn1,
                 float2* __restrict__ part, float* __restrict__ ymax,
                 float* __restrict__ ymin) {
  __shared__ ushort x_lds[ROWS * XS];   // 75776 B; also holds 128x258 y tile
  __shared__ float bn_lds[2 * DC];

  const int grp = blockIdx.x;           // 0..NG-1
  const int bp0 = grp * 4;
  const int b = bp0 >> 10;
  const int tid = threadIdx.x;
  const int lane = tid & 63;
  const int wv = tid >> 6;
  const int l15 = lane & 15;
  const int l4 = lane >> 4;

  for (int i = tid; i < 2 * DC; i += 256) bn_lds[i] = bn1[i];

  // ---- gather feats: 8 threads/row, 128-B coalesced segments ----
  {
    int q = tid & 7;
#pragma unroll
    for (int rep = 0; rep < 4; ++rep) {
      int s = (tid >> 3) + rep * 32;
      int j = idxp[(size_t)bp0 * DNS + s];
      const uint4* src = ftb + (size_t)(b * DN + j) * (DC / 8);
      uint4* dst = (uint4*)(x_lds + (size_t)s * XS);
#pragma unroll
      for (int k = 0; k < 4; ++k) dst[q + 8 * k] = src[q + 8 * k];
    }
  }
  // ---- gx channels at k=256..258, zeros to 287 ----
  if (tid < ROWS) {
    const float* g = gxp + ((size_t)bp0 * DNS + tid) * 3;
    uint a0 = (uint)f2b(g[0]) | ((uint)f2b(g[1]) << 16);
    uint a1 = (uint)f2b(g[2]);
    uint4* drow = (uint4*)(x_lds + (size_t)tid * XS + 256);
    drow[0] = make_uint4(a0, a1, 0u, 0u);
    drow[1] = make_uint4(0u, 0u, 0u, 0u);
    drow[2] = make_uint4(0u, 0u, 0u, 0u);
    drow[3] = make_uint4(0u, 0u, 0u, 0u);
  }
  __syncthreads();

  f32x4 acc[4][8];
#pragma unroll
  for (int t = 0; t < 4; ++t)
#pragma unroll
    for (int st = 0; st < 8; ++st)
#pragma unroll
      for (int r = 0; r < 4; ++r) acc[t][st][r] = 0.f;

  const int o0 = wv * 64;
  const ushort* xbase = x_lds + (size_t)l15 * XS + l4 * 8;

  // ---- GEMM1: K = 288, 9 K-steps of 32; A prefetched one step ahead ----
  {
    const ushort* wrow[4];
#pragma unroll
    for (int t = 0; t < 4; ++t)
      wrow[t] = W1b + (size_t)(o0 + t * 16 + l15) * K1 + l4 * 8;
    bf16x8 aw[4];
#pragma unroll
    for (int t = 0; t < 4; ++t) aw[t] = *(const bf16x8*)(wrow[t]);
#pragma unroll
    for (int ks = 0; ks < NK1; ++ks) {
      bf16x8 bx[8];
#pragma unroll
      for (int st = 0; st < 8; ++st)
        bx[st] = *(const bf16x8*)(xbase + (size_t)st * 16 * XS + ks * 32);
      bf16x8 an[4];
      if (ks + 1 < NK1) {
#pragma unroll
        for (int t = 0; t < 4; ++t)
          an[t] = *(const bf16x8*)(wrow[t] + (ks + 1) * 32);
      }
#pragma unroll
      for (int st = 0; st < 8; ++st)
#pragma unroll
        for (int t = 0; t < 4; ++t)
          acc[t][st] = __builtin_amdgcn_mfma_f32_16x16x32_bf16(aw[t], bx[st],
                                                               acc[t][st], 0, 0, 0);
      if (ks + 1 < NK1) {
#pragma unroll
        for (int t = 0; t < 4; ++t) aw[t] = an[t];
      }
    }
  }

  // ---- bn1 + relu -> x2 (bf16) back into x_lds[s][o] (stride XS) ----
  __syncthreads();  // all GEMM1 LDS reads complete before overwrite
#pragma unroll
  for (int t = 0; t < 4; ++t) {
    int ob = o0 + t * 16 + l4 * 4;
    float sc0 = bn_lds[ob + 0], sh0 = bn_lds[DC + ob + 0];
    float sc1 = bn_lds[ob + 1], sh1 = bn_lds[DC + ob + 1];
    float sc2 = bn_lds[ob + 2], sh2 = bn_lds[DC + ob + 2];
    float sc3 = bn_lds[ob + 3], sh3 = bn_lds[DC + ob + 3];
#pragma unroll
    for (int st = 0; st < 8; ++st) {
      float v0 = fmaxf(fmaf(acc[t][st][0], sc0, sh0), 0.f);
      float v1 = fmaxf(fmaf(acc[t][st][1], sc1, sh1), 0.f);
      float v2 = fmaxf(fmaf(acc[t][st][2], sc2, sh2), 0.f);
      float v3 = fmaxf(fmaf(acc[t][st][3], sc3, sh3), 0.f);
      uint2 pk = make_uint2((uint)f2b(v0) | ((uint)f2b(v1) << 16),
                            (uint)f2b(v2) | ((uint)f2b(v3) << 16));
      int s = st * 16 + l15;
      *(uint2*)(x_lds + (size_t)s * XS + ob) = pk;
      acc[t][st][0] = 0.f; acc[t][st][1] = 0.f;
      acc[t][st][2] = 0.f; acc[t][st][3] = 0.f;
    }
  }
  __syncthreads();

  // ---- GEMM2: K = 256, 8 K-steps ----
  {
    const ushort* wrow[4];
#pragma unroll
    for (int t = 0; t < 4; ++t)
      wrow[t] = W2b + (size_t)(o0 + t * 16 + l15) * K2 + l4 * 8;
    bf16x8 aw[4];
#pragma unroll
    for (int t = 0; t < 4; ++t) aw[t] = *(const bf16x8*)(wrow[t]);
#pragma unroll
    for (int ks = 0; ks < NK2; ++ks) {
      bf16x8 bx[8];
#pragma unroll
      for (int st = 0; st < 8; ++st)
        bx[st] = *(const bf16x8*)(xbase + (size_t)st * 16 * XS + ks * 32);
      bf16x8 an[4];
      if (ks + 1 < NK2) {
#pragma unroll
        for (int t = 0; t < 4; ++t)
          an[t] = *(const bf16x8*)(wrow[t] + (ks + 1) * 32);
      }
#pragma unroll
      for (int st = 0; st < 8; ++st)
#pragma unroll
        for (int t = 0; t < 4; ++t)
          acc[t][st] = __builtin_amdgcn_mfma_f32_16x16x32_bf16(aw[t], bx[st],
                                                               acc[t][st], 0, 0, 0);
      if (ks + 1 < NK2) {
#pragma unroll
        for (int t = 0; t < 4; ++t) aw[t] = an[t];
      }
    }
  }

  // ---- y2 -> bf16 [s][o] tile, then per-o column stats + per-bp max/min ----
  __syncthreads();
#pragma unroll
  for (int t = 0; t < 4; ++t) {
    int ob = o0 + t * 16 + l4 * 4;
#pragma unroll
    for (int st = 0; st < 8; ++st) {
      uint2 pk = make_uint2(
          (uint)f2b(acc[t][st][0]) | ((uint)f2b(acc[t][st][1]) << 16),
          (uint)f2b(acc[t][st][2]) | ((uint)f2b(acc[t][st][3]) << 16));
      int s = st * 16 + l15;
      *(uint2*)(x_lds + (size_t)s * YS + ob) = pk;
    }
  }
  __syncthreads();
  {
    const ushort* col = x_lds + tid;  // o = tid
    float s = 0.f, q = 0.f;
#pragma unroll
    for (int p = 0; p < 4; ++p) {
      float mx = -3.4e38f, mn = 3.4e38f;
#pragma unroll 8
      for (int i = 0; i < DNS; ++i) {
        float v = b2f(col[(size_t)(p * DNS + i) * YS]);
        s += v; q += v * v;
        mx = fmaxf(mx, v); mn = fminf(mn, v);
      }
      ymax[(size_t)(bp0 + p) * DC + tid] = mx;
      ymin[(size_t)(bp0 + p) * DC + tid] = mn;
    }
    part[(size_t)grp * DC + tid] = make_float2(s, q);
  }
}

// ---------------------------------------------------------------------------
__global__ void k_reduce_bn(const float* __restrict__ part, const float* __restrict__ gam,
                            const float* __restrict__ bet, float* __restrict__ bn) {
  int o = blockIdx.x, tid = threadIdx.x;
  __shared__ float ss[256], sq[256];
  float s = 0.f, q = 0.f;
  const float2* pp = (const float2*)part;
  for (int g = tid; g < NG; g += 256) {
    float2 v = pp[(size_t)g * DC + o];
    s += v.x; q += v.y;
  }
  ss[tid] = s; sq[tid] = q;
  __syncthreads();
  for (int w = 128; w > 0; w >>= 1) {
    if (tid < w) { ss[tid] += ss[tid + w]; sq[tid] += sq[tid + w]; }
    __syncthreads();
  }
  if (tid == 0) {
    float mu = ss[0] * kInvCnt;
    float var = sq[0] * kInvCnt - mu * mu;
    var = var < 0.f ? 0.f : var;
    float sc = gam[o] * rsqrtf(var + kEps);
    bn[o] = sc;
    bn[DC + o] = bet[o] - mu * sc;
  }
}

// ---------------------------------------------------------------------------
__global__ void k_final(const float* __restrict__ ymax, const float* __restrict__ ymin,
                        const float* __restrict__ bn2, float* __restrict__ out) {
  __shared__ float tmax[32][33], tmin[32][33];
  int ot = blockIdx.x, pt = blockIdx.y, b = blockIdx.z;
  int tx = threadIdx.x, ty = threadIdx.y;  // 32 x 8
#pragma unroll
  for (int k = 0; k < 4; ++k) {
    int pr = ty + k * 8;
    size_t base = ((size_t)(b * DP) + pt * 32 + pr) * DC + ot * 32 + tx;
    tmax[pr][tx] = ymax[base];
    tmin[pr][tx] = ymin[base];
  }
  __syncthreads();
#pragma unroll
  for (int k = 0; k < 4; ++k) {
    int oc = ty + k * 8;
    int o = ot * 32 + oc;
    float sc = bn2[o], sh = bn2[DC + o];
    float m = (sc >= 0.f) ? tmax[tx][oc] : tmin[tx][oc];
    float v = fmaf(sc, m, sh);
    v = v > 0.f ? v : 0.f;
    out[((size_t)(b * DC) + o) * DP + pt * 32 + tx] = v;
  }
}

// ---------------------------------------------------------------------------
extern "C" void kernel_launch(void* const* d_in, const int* in_sizes, int n_in,
                              void* d_out, int out_size, void* d_ws, size_t ws_size,
                              hipStream_t stream) {
  const float* xyz   = (const float*)d_in[0];
  const float* feats = (const float*)d_in[1];
  const float* rot   = (const float*)d_in[2];
  const float* W1    = (const float*)d_in[3];
  const float* g1    = (const float*)d_in[4];
  const float* b1    = (const float*)d_in[5];
  const float* W2    = (const float*)d_in[6];
  const float* g2    = (const float*)d_in[7];
  const float* b2    = (const float*)d_in[8];
  float* out = (float*)d_out;

  float* ws = (float*)d_ws;
  uint*   ftb_u  = (uint*)(ws + OF_FEATST);
  uint4*  ftb    = (uint4*)(ws + OF_FEATST);
  ushort* W1b    = (ushort*)(ws + OF_W1B);
  ushort* W2b    = (ushort*)(ws + OF_W2B);
  int*    idxp   = (int*)(ws + OF_IDX);
  float*  gxp    = ws + OF_GX;
  float2* partp  = (float2*)(ws + OF_PART);
  float*  ymaxp  = ws + OF_YMAX;
  float*  yminp  = ws + OF_YMIN;
  float*  bn1p   = ws + OF_BN1;
  float*  bn2p   = ws + OF_BN2;
  float*  cntp   = ws + OF_CNT;
  float*  gwp    = ws + OF_GW;
  float*  ggp    = ws + OF_GG;
  float*  cmp    = ws + OF_CM;

  k_transpose_feats<<<dim3(DC / 32, DN / 32, DB), dim3(32, 8), 0, stream>>>(feats, ftb_u);
  k_prep_w1<<<(DC * K1 + 255) / 256, 256, 0, stream>>>(W1, W1b);
  k_prep_w2<<<(DC * K2 + 255) / 256, 256, 0, stream>>>(W2, W2b);
  k_query<<<DBP, 64, 0, stream>>>(xyz, rot, idxp, gxp);

  // ---- bn1 stats via count algebra (no GEMM1 stats pass) ----
  k_zero<<<(ZN + 255) / 256, 256, 0, stream>>>(cntp, ZN);
  k_count<<<DBP * DNS / 1024, 256, 0, stream>>>(idxp, gxp, cntp, gwp, ggp);
  k_xxt<<<dim3(5, 5, 32), 256, 0, stream>>>(feats, cntp, gwp, cmp);
  k_bn1<<<DC, 256, 0, stream>>>(cmp, ggp, W1, g1, b1, bn1p);

  // ---- fused GEMM1+bn1+relu+GEMM2 + y2 stats/max/min ----
  k_gemm_full<<<NG, 256, 0, stream>>>(ftb, W1b, W2b, idxp, gxp, bn1p, partp,
                                      ymaxp, yminp);
  k_reduce_bn<<<DC, 256, 0, stream>>>((const float*)partp, g2, b2, bn2p);
  k_final<<<dim3(DC / 32, DP / 32, DB), dim3(32, 8), 0, stream>>>(ymaxp, yminp, bn2p, out);
}

// Round 8
// 198.294 us; speedup vs baseline: 1.3108x; 1.3108x over previous
//
#include <hip/hip_runtime.h>
#include <hip/hip_bf16.h>

#define DB 8
#define DN 1024
#define DP 1024
#define DC 256
#define DNS 32
#define DBP (DB * DP)
#define K1 288   // padded GEMM1 K (256 feats + 3 gx + 29 zeros)
#define K2 256
#define XS 296   // x_lds row stride in bf16 elems (592 B; 148 dwords == 20 mod 32)
#define YS 258   // epilogue y-tile row stride in bf16 (129 dwords == 1 mod 32)
#define ROWS 128 // 4 bp per block (round-5 best config)
#define NG (DBP / 4)
#define NK1 (K1 / 32)  // 9
#define NK2 (K2 / 32)  // 8
#define CME (257 * 259)

constexpr float kRadius = 0.05f;
constexpr float kR2 = kRadius * kRadius;
constexpr float kHmin = -0.02f;
constexpr float kHmax = 0.04f;
constexpr float kEps = 1e-5f;
constexpr float kInvCnt = 1.0f / (float)(DB * DP * DNS);

typedef __bf16 bf16x8 __attribute__((ext_vector_type(8)));
typedef float f32x4 __attribute__((ext_vector_type(4)));
static_assert(sizeof(bf16x8) == 16, "bf16x8 must be 16B");

// ---- workspace layout (in floats) ----
constexpr size_t OF_FEATST = 0;                                   // B*N*C bf16
constexpr size_t OF_W1B  = OF_FEATST + (size_t)DB * DN * DC / 2;  // DC*K1 bf16
constexpr size_t OF_W2B  = OF_W1B + (size_t)DC * K1 / 2;          // DC*K2 bf16
constexpr size_t OF_IDX  = OF_W2B + (size_t)DC * K2 / 2;          // BP*NS int32
constexpr size_t OF_GX   = OF_IDX + (size_t)DBP * DNS;            // BP*NS*3
constexpr size_t OF_PART = OF_GX + (size_t)DBP * DNS * 3;         // NG*C*2
constexpr size_t OF_YMAX = OF_PART + (size_t)DBP * DC * 2;        // BP*C
constexpr size_t OF_YMIN = OF_YMAX + (size_t)DBP * DC;            // BP*C
constexpr size_t OF_BN1  = OF_YMIN + (size_t)DBP * DC;            // 512
constexpr size_t OF_BN2  = OF_BN1 + 512;                          // 512
// ---- stats-via-counts scratch ----
constexpr size_t OF_CNT  = OF_BN2 + 512;                          // B*N
constexpr size_t OF_GW   = OF_CNT + (size_t)DB * DN;              // B*3*N
constexpr size_t OF_GG   = OF_GW + (size_t)DB * 3 * DN;           // 16 (use 9)
constexpr size_t OF_CM   = OF_GG + 16;                            // 257*259
constexpr int    ZN      = DB * DN + DB * 3 * DN + 16;
// Cmz slices (32 x 257*259 = 8.5MB) alias the ymax/ymin region: stats phase
// completes before k_gemm_full writes ymax/ymin (stream-ordered).

__device__ inline ushort f2b(float x) {
  union { __hip_bfloat16 h; ushort u; } c;
  c.h = __float2bfloat16(x);
  return c.u;
}
__device__ inline float b2f(ushort u) {
  union { uint u; float f; } c;
  c.u = (uint)u << 16;
  return c.f;
}

// ---------------------------------------------------------------------------
// feats (B,C,N) f32 -> featsTb (B,N,C) bf16 via LDS tile transpose
__global__ void k_transpose_feats(const float* __restrict__ f, uint* __restrict__ ftb) {
  __shared__ float t[32][33];
  int ct = blockIdx.x, nt = blockIdx.y, b = blockIdx.z;
  int tx = threadIdx.x, ty = threadIdx.y;  // 32 x 8
#pragma unroll
  for (int k = 0; k < 4; ++k) {
    int c = ct * 32 + ty + k * 8;
    t[ty + k * 8][tx] = f[((size_t)b * DC + c) * DN + nt * 32 + tx];
  }
  __syncthreads();
  int tid = ty * 32 + tx;
  uint* dst = ftb + (size_t)b * DN * (DC / 2);
#pragma unroll
  for (int it = 0; it < 2; ++it) {
    int idx = it * 256 + tid;
    int nl = idx >> 4, cp = idx & 15;
    uint v = (uint)f2b(t[2 * cp][nl]) | ((uint)f2b(t[2 * cp + 1][nl]) << 16);
    dst[(size_t)(nt * 32 + nl) * (DC / 2) + ct * 16 + cp] = v;
  }
}

// W1 (256,259) f32 -> W1b (256,K1) bf16, K permuted: k'=0..255 <- k=3..258,
// k'=256..258 <- k=0..2 (gx), rest zero
__global__ void k_prep_w1(const float* __restrict__ W1, ushort* __restrict__ W1b) {
  int gid = blockIdx.x * 256 + threadIdx.x;
  if (gid >= DC * K1) return;
  int o = gid / K1, kp = gid - o * K1;
  float v = 0.f;
  if (kp < 256) v = W1[o * 259 + 3 + kp];
  else if (kp < 259) v = W1[o * 259 + (kp - 256)];
  W1b[gid] = f2b(v);
}

__global__ void k_prep_w2(const float* __restrict__ W2, ushort* __restrict__ W2b) {
  int gid = blockIdx.x * 256 + threadIdx.x;
  if (gid >= DC * K2) return;
  W2b[gid] = f2b(W2[gid]);
}

// ---------------------------------------------------------------------------
// cylinder query + grouped/rotated xyz. One wave per (b,p).
__global__ void k_query(const float* __restrict__ xyz, const float* __restrict__ rot,
                        int* __restrict__ idxp, float* __restrict__ gxp) {
  int bp = blockIdx.x;
  int b = bp >> 10;
  int lane = threadIdx.x;
  __shared__ int sidx[DNS];
  __shared__ float srot[9], sc[3];
  if (lane < DNS) sidx[lane] = 0;
  if (lane < 9) srot[lane] = rot[(size_t)bp * 9 + lane];
  if (lane < 3) sc[lane] = xyz[(size_t)bp * 3 + lane];
  __syncthreads();
  float r00 = srot[0], r01 = srot[1], r02 = srot[2];
  float r10 = srot[3], r11 = srot[4], r12 = srot[5];
  float r20 = srot[6], r21 = srot[7], r22 = srot[8];
  float cx = sc[0], cy = sc[1], cz = sc[2];
  const float* xb = xyz + (size_t)b * DN * 3;
  int cnt = 0;
  for (int ch = 0; ch < DN / 64 && cnt < DNS; ++ch) {
    int n = ch * 64 + lane;
    float dx = xb[n * 3 + 0] - cx, dy = xb[n * 3 + 1] - cy, dz = xb[n * 3 + 2] - cz;
    float lx = dx * r00 + dy * r10 + dz * r20;
    float ly = dx * r01 + dy * r11 + dz * r21;
    float lz = dx * r02 + dy * r12 + dz * r22;
    bool m = (ly * ly + lz * lz < kR2) && (lx > kHmin) && (lx < kHmax);
    unsigned long long bal = __ballot(m);
    int rank = cnt + __popcll(bal & ((1ull << lane) - 1ull));
    if (m && rank < DNS) sidx[rank] = n;
    cnt += __popcll(bal);
  }
  __syncthreads();
  if (lane < DNS) {
    int j = sidx[lane];
    idxp[(size_t)bp * DNS + lane] = j;
    float gx = (xb[j * 3 + 0] - cx) / kRadius;
    float gy = (xb[j * 3 + 1] - cy) / kRadius;
    float gz = (xb[j * 3 + 2] - cz) / kRadius;
    float* gp = gxp + ((size_t)bp * DNS + lane) * 3;
    gp[0] = gx * r00 + gy * r10 + gz * r20;
    gp[1] = gx * r01 + gy * r11 + gz * r21;
    gp[2] = gx * r02 + gy * r12 + gz * r22;
  }
}

// ---------------------------------------------------------------------------
// zero scratch for the stats pipeline
__global__ void k_zero(float* __restrict__ p, int n) {
  int i = blockIdx.x * 256 + threadIdx.x;
  if (i < n) p[i] = 0.f;
}

// counts + weighted-gx sums per (b, point) via per-block LDS histogram
// (hot j=0 from empty-slot padding serializes in LDS, not L2);
// gx*gx^T 3x3 global sum. 256 blocks x 256 threads x 4 samples each;
// each block covers 1024 consecutive samples = 32 bp = single batch.
__global__ __launch_bounds__(256)
void k_count(const int* __restrict__ idxp, const float* __restrict__ gxp,
             float* __restrict__ cnt, float* __restrict__ gw, float* __restrict__ gg) {
  __shared__ float h0[DN], h1[DN], h2[DN], h3[DN];
  int t = threadIdx.x;
  int b = blockIdx.x >> 5;  // 32 blocks per batch
  for (int i = t; i < DN; i += 256) {
    h0[i] = 0.f; h1[i] = 0.f; h2[i] = 0.f; h3[i] = 0.f;
  }
  __syncthreads();
  float p[6] = {0.f, 0.f, 0.f, 0.f, 0.f, 0.f};
#pragma unroll
  for (int r = 0; r < 4; ++r) {
    int sid = blockIdx.x * 1024 + r * 256 + t;
    int j = idxp[sid];
    const float* g = gxp + (size_t)sid * 3;
    float g0 = g[0], g1 = g[1], g2 = g[2];
    atomicAdd(&h0[j], 1.f);
    atomicAdd(&h1[j], g0);
    atomicAdd(&h2[j], g1);
    atomicAdd(&h3[j], g2);
    p[0] += g0 * g0; p[1] += g0 * g1; p[2] += g0 * g2;
    p[3] += g1 * g1; p[4] += g1 * g2; p[5] += g2 * g2;
  }
  __syncthreads();
  for (int i = t; i < DN; i += 256) {
    float c = h0[i];
    if (c != 0.f) {
      atomicAdd(&cnt[b * DN + i], c);
      atomicAdd(&gw[(b * 3 + 0) * DN + i], h1[i]);
      atomicAdd(&gw[(b * 3 + 1) * DN + i], h2[i]);
      atomicAdd(&gw[(b * 3 + 2) * DN + i], h3[i]);
    }
  }
  __shared__ float sgg[4][6];
#pragma unroll
  for (int v = 0; v < 6; ++v) {
    float s = p[v];
#pragma unroll
    for (int m = 1; m < 64; m <<= 1) s += __shfl_xor(s, m, 64);
    if ((t & 63) == 0) sgg[t >> 6][v] = s;
  }
  __syncthreads();
  if (t < 6) {
    float s = sgg[0][t] + sgg[1][t] + sgg[2][t] + sgg[3][t];
    const int i1[6] = {0, 1, 2, 4, 5, 8};  // (0,0)(0,1)(0,2)(1,1)(1,2)(2,2)
    const int i2[6] = {0, 3, 6, 4, 7, 8};
    atomicAdd(&gg[i1[t]], s);
    if (i2[t] != i1[t]) atomicAdd(&gg[i2[t]], s);
  }
}

// Cmz[z] = F'(257x1024-quarter) * P^T slice: F' rows 0..255 = feats, 256 = ones;
// P cols: k2<256 -> feats*cnt, 256..258 -> gw. grid (5,5,32): z = batch*4+quarter.
// Plain stores into per-z slice (no atomics); k_sumcm folds slices.
__global__ __launch_bounds__(256)
void k_xxt(const float* __restrict__ feats, const float* __restrict__ cnt,
           const float* __restrict__ gw, float* __restrict__ Cmz) {
  __shared__ float As[16][65], Bs[16][65];
  int bt = blockIdx.z >> 2;
  int n0 = (blockIdx.z & 3) * 256;
  int r0 = blockIdx.x * 64, c0 = blockIdx.y * 64;
  int tid = threadIdx.x;
  int ty = tid >> 4, tx = tid & 15;
  int li = tid >> 2, lq = tid & 3;
  const float* fb = feats + (size_t)bt * DC * DN;
  const float* cb = cnt + (size_t)bt * DN;
  const float* gb = gw + (size_t)bt * 3 * DN;
  float acc[4][4];
#pragma unroll
  for (int u = 0; u < 4; ++u)
#pragma unroll
    for (int v = 0; v < 4; ++v) acc[u][v] = 0.f;

  for (int nc = n0; nc < n0 + 256; nc += 16) {
    __syncthreads();
    {
      int k1 = r0 + li;
      float4 av = make_float4(0.f, 0.f, 0.f, 0.f);
      if (k1 < 256) av = *(const float4*)(fb + (size_t)k1 * DN + nc + lq * 4);
      else if (k1 == 256) av = make_float4(1.f, 1.f, 1.f, 1.f);
      As[lq * 4 + 0][li] = av.x; As[lq * 4 + 1][li] = av.y;
      As[lq * 4 + 2][li] = av.z; As[lq * 4 + 3][li] = av.w;
      int k2 = c0 + li;
      float4 bv = make_float4(0.f, 0.f, 0.f, 0.f);
      if (k2 < 256) {
        float4 f = *(const float4*)(fb + (size_t)k2 * DN + nc + lq * 4);
        float4 c4 = *(const float4*)(cb + nc + lq * 4);
        bv = make_float4(f.x * c4.x, f.y * c4.y, f.z * c4.z, f.w * c4.w);
      } else if (k2 < 259) {
        bv = *(const float4*)(gb + (size_t)(k2 - 256) * DN + nc + lq * 4);
      }
      Bs[lq * 4 + 0][li] = bv.x; Bs[lq * 4 + 1][li] = bv.y;
      Bs[lq * 4 + 2][li] = bv.z; Bs[lq * 4 + 3][li] = bv.w;
    }
    __syncthreads();
#pragma unroll
    for (int kk = 0; kk < 16; ++kk) {
      float a[4], bvv[4];
#pragma unroll
      for (int u = 0; u < 4; ++u) a[u] = As[kk][ty * 4 + u];
#pragma unroll
      for (int v = 0; v < 4; ++v) bvv[v] = Bs[kk][tx * 4 + v];
#pragma unroll
      for (int u = 0; u < 4; ++u)
#pragma unroll
        for (int v = 0; v < 4; ++v) acc[u][v] = fmaf(a[u], bvv[v], acc[u][v]);
    }
  }
  float* dst = Cmz + (size_t)blockIdx.z * CME;
#pragma unroll
  for (int u = 0; u < 4; ++u) {
    int k1 = r0 + ty * 4 + u;
    if (k1 > 256) continue;
#pragma unroll
    for (int v = 0; v < 4; ++v) {
      int k2 = c0 + tx * 4 + v;
      if (k2 < 259) dst[(size_t)k1 * 259 + k2] = acc[u][v];
    }
  }
}

// fold the 32 Cmz slices -> Cm
__global__ void k_sumcm(const float* __restrict__ Cmz, float* __restrict__ Cm) {
  int e = blockIdx.x * 256 + threadIdx.x;
  if (e >= CME) return;
  float s = 0.f;
  for (int z = 0; z < 32; ++z) s += Cmz[(size_t)z * CME + e];
  Cm[e] = s;
}

// per-channel bn1 scale/shift from C, gg: mu = w.sumx/N, Ey2 = w^T M w / N
__global__ __launch_bounds__(256)
void k_bn1(const float* __restrict__ Cm, const float* __restrict__ gg,
           const float* __restrict__ W1, const float* __restrict__ gam,
           const float* __restrict__ bet, float* __restrict__ bn) {
  int o = blockIdx.x, t = threadIdx.x;
  __shared__ float wv[259];
  __shared__ float rq[256], rs[256];
  for (int j = t; j < 259; j += 256)
    wv[j] = (j < 256) ? W1[o * 259 + 3 + j] : W1[o * 259 + (j - 256)];
  __syncthreads();
  float qp = 0.f, sp = 0.f;
  for (int j = t; j < 259; j += 256) {
    float u = 0.f;
    for (int i = 0; i < 256; ++i) u = fmaf(wv[i], Cm[(size_t)i * 259 + j], u);
#pragma unroll
    for (int c = 0; c < 3; ++c) {
      float m = (j < 256) ? Cm[(size_t)j * 259 + 256 + c] : gg[c * 3 + (j - 256)];
      u = fmaf(wv[256 + c], m, u);
    }
    qp = fmaf(wv[j], u, qp);
    sp = fmaf(wv[j], Cm[(size_t)256 * 259 + j], sp);
  }
  rq[t] = qp; rs[t] = sp;
  __syncthreads();
  for (int w = 128; w > 0; w >>= 1) {
    if (t < w) { rq[t] += rq[t + w]; rs[t] += rs[t + w]; }
    __syncthreads();
  }
  if (t == 0) {
    float mu = rs[0] * kInvCnt;
    float var = rq[0] * kInvCnt - mu * mu;
    var = var < 0.f ? 0.f : var;
    float sc = gam[o] * rsqrtf(var + kEps);
    bn[o] = sc;
    bn[DC + o] = bet[o] - mu * sc;
  }
}

// ---------------------------------------------------------------------------
// MFMA GEMM over 4 bp per block (128 sample rows), 16x16x32 bf16 — round-5 FULL.
// 256 threads = 4 waves; wave w owns o-range w*64 (4 o-tiles of 16), 8 s-tiles.
// D layout: col = lane&15 (=s), row = (lane>>4)*4 + reg (=o).
__global__ __launch_bounds__(256, 2)
void k_gemm_full(const uint4* __restrict__ ftb, const ushort* __restrict__ W1b,
                 const ushort* __restrict__ W2b, const int* __restrict__ idxp,
                 const float* __restrict__ gxp, const float* __restrict__ bn1,
                 float2* __restrict__ part, float* __restrict__ ymax,
                 float* __restrict__ ymin) {
  __shared__ ushort x_lds[ROWS * XS];   // 75776 B; also holds 128x258 y tile
  __shared__ float bn_lds[2 * DC];

  const int grp = blockIdx.x;           // 0..NG-1
  const int bp0 = grp * 4;
  const int b = bp0 >> 10;
  const int tid = threadIdx.x;
  const int lane = tid & 63;
  const int wv = tid >> 6;
  const int l15 = lane & 15;
  const int l4 = lane >> 4;

  for (int i = tid; i < 2 * DC; i += 256) bn_lds[i] = bn1[i];

  // ---- gather feats: 8 threads/row, 128-B coalesced segments ----
  {
    int q = tid & 7;
#pragma unroll
    for (int rep = 0; rep < 4; ++rep) {
      int s = (tid >> 3) + rep * 32;
      int j = idxp[(size_t)bp0 * DNS + s];
      const uint4* src = ftb + (size_t)(b * DN + j) * (DC / 8);
      uint4* dst = (uint4*)(x_lds + (size_t)s * XS);
#pragma unroll
      for (int k = 0; k < 4; ++k) dst[q + 8 * k] = src[q + 8 * k];
    }
  }
  // ---- gx channels at k=256..258, zeros to 287 ----
  if (tid < ROWS) {
    const float* g = gxp + ((size_t)bp0 * DNS + tid) * 3;
    uint a0 = (uint)f2b(g[0]) | ((uint)f2b(g[1]) << 16);
    uint a1 = (uint)f2b(g[2]);
    uint4* drow = (uint4*)(x_lds + (size_t)tid * XS + 256);
    drow[0] = make_uint4(a0, a1, 0u, 0u);
    drow[1] = make_uint4(0u, 0u, 0u, 0u);
    drow[2] = make_uint4(0u, 0u, 0u, 0u);
    drow[3] = make_uint4(0u, 0u, 0u, 0u);
  }
  __syncthreads();

  f32x4 acc[4][8];
#pragma unroll
  for (int t = 0; t < 4; ++t)
#pragma unroll
    for (int st = 0; st < 8; ++st)
#pragma unroll
      for (int r = 0; r < 4; ++r) acc[t][st][r] = 0.f;

  const int o0 = wv * 64;
  const ushort* xbase = x_lds + (size_t)l15 * XS + l4 * 8;

  // ---- GEMM1: K = 288, 9 K-steps of 32; A prefetched one step ahead ----
  {
    const ushort* wrow[4];
#pragma unroll
    for (int t = 0; t < 4; ++t)
      wrow[t] = W1b + (size_t)(o0 + t * 16 + l15) * K1 + l4 * 8;
    bf16x8 aw[4];
#pragma unroll
    for (int t = 0; t < 4; ++t) aw[t] = *(const bf16x8*)(wrow[t]);
#pragma unroll
    for (int ks = 0; ks < NK1; ++ks) {
      bf16x8 bx[8];
#pragma unroll
      for (int st = 0; st < 8; ++st)
        bx[st] = *(const bf16x8*)(xbase + (size_t)st * 16 * XS + ks * 32);
      bf16x8 an[4];
      if (ks + 1 < NK1) {
#pragma unroll
        for (int t = 0; t < 4; ++t)
          an[t] = *(const bf16x8*)(wrow[t] + (ks + 1) * 32);
      }
#pragma unroll
      for (int st = 0; st < 8; ++st)
#pragma unroll
        for (int t = 0; t < 4; ++t)
          acc[t][st] = __builtin_amdgcn_mfma_f32_16x16x32_bf16(aw[t], bx[st],
                                                               acc[t][st], 0, 0, 0);
      if (ks + 1 < NK1) {
#pragma unroll
        for (int t = 0; t < 4; ++t) aw[t] = an[t];
      }
    }
  }

  // ---- bn1 + relu -> x2 (bf16) back into x_lds[s][o] (stride XS) ----
  __syncthreads();  // all GEMM1 LDS reads complete before overwrite
#pragma unroll
  for (int t = 0; t < 4; ++t) {
    int ob = o0 + t * 16 + l4 * 4;
    float sc0 = bn_lds[ob + 0], sh0 = bn_lds[DC + ob + 0];
    float sc1 = bn_lds[ob + 1], sh1 = bn_lds[DC + ob + 1];
    float sc2 = bn_lds[ob + 2], sh2 = bn_lds[DC + ob + 2];
    float sc3 = bn_lds[ob + 3], sh3 = bn_lds[DC + ob + 3];
#pragma unroll
    for (int st = 0; st < 8; ++st) {
      float v0 = fmaxf(fmaf(acc[t][st][0], sc0, sh0), 0.f);
      float v1 = fmaxf(fmaf(acc[t][st][1], sc1, sh1), 0.f);
      float v2 = fmaxf(fmaf(acc[t][st][2], sc2, sh2), 0.f);
      float v3 = fmaxf(fmaf(acc[t][st][3], sc3, sh3), 0.f);
      uint2 pk = make_uint2((uint)f2b(v0) | ((uint)f2b(v1) << 16),
                            (uint)f2b(v2) | ((uint)f2b(v3) << 16));
      int s = st * 16 + l15;
      *(uint2*)(x_lds + (size_t)s * XS + ob) = pk;
      acc[t][st][0] = 0.f; acc[t][st][1] = 0.f;
      acc[t][st][2] = 0.f; acc[t][st][3] = 0.f;
    }
  }
  __syncthreads();

  // ---- GEMM2: K = 256, 8 K-steps ----
  {
    const ushort* wrow[4];
#pragma unroll
    for (int t = 0; t < 4; ++t)
      wrow[t] = W2b + (size_t)(o0 + t * 16 + l15) * K2 + l4 * 8;
    bf16x8 aw[4];
#pragma unroll
    for (int t = 0; t < 4; ++t) aw[t] = *(const bf16x8*)(wrow[t]);
#pragma unroll
    for (int ks = 0; ks < NK2; ++ks) {
      bf16x8 bx[8];
#pragma unroll
      for (int st = 0; st < 8; ++st)
        bx[st] = *(const bf16x8*)(xbase + (size_t)st * 16 * XS + ks * 32);
      bf16x8 an[4];
      if (ks + 1 < NK2) {
#pragma unroll
        for (int t = 0; t < 4; ++t)
          an[t] = *(const bf16x8*)(wrow[t] + (ks + 1) * 32);
      }
#pragma unroll
      for (int st = 0; st < 8; ++st)
#pragma unroll
        for (int t = 0; t < 4; ++t)
          acc[t][st] = __builtin_amdgcn_mfma_f32_16x16x32_bf16(aw[t], bx[st],
                                                               acc[t][st], 0, 0, 0);
      if (ks + 1 < NK2) {
#pragma unroll
        for (int t = 0; t < 4; ++t) aw[t] = an[t];
      }
    }
  }

  // ---- y2 -> bf16 [s][o] tile, then per-o column stats + per-bp max/min ----
  __syncthreads();
#pragma unroll
  for (int t = 0; t < 4; ++t) {
    int ob = o0 + t * 16 + l4 * 4;
#pragma unroll
    for (int st = 0; st < 8; ++st) {
      uint2 pk = make_uint2(
          (uint)f2b(acc[t][st][0]) | ((uint)f2b(acc[t][st][1]) << 16),
          (uint)f2b(acc[t][st][2]) | ((uint)f2b(acc[t][st][3]) << 16));
      int s = st * 16 + l15;
      *(uint2*)(x_lds + (size_t)s * YS + ob) = pk;
    }
  }
  __syncthreads();
  {
    const ushort* col = x_lds + tid;  // o = tid
    float s = 0.f, q = 0.f;
#pragma unroll
    for (int p = 0; p < 4; ++p) {
      float mx = -3.4e38f, mn = 3.4e38f;
#pragma unroll 8
      for (int i = 0; i < DNS; ++i) {
        float v = b2f(col[(size_t)(p * DNS + i) * YS]);
        s += v; q += v * v;
        mx = fmaxf(mx, v); mn = fminf(mn, v);
      }
      ymax[(size_t)(bp0 + p) * DC + tid] = mx;
      ymin[(size_t)(bp0 + p) * DC + tid] = mn;
    }
    part[(size_t)grp * DC + tid] = make_float2(s, q);
  }
}

// ---------------------------------------------------------------------------
__global__ void k_reduce_bn(const float* __restrict__ part, const float* __restrict__ gam,
                            const float* __restrict__ bet, float* __restrict__ bn) {
  int o = blockIdx.x, tid = threadIdx.x;
  __shared__ float ss[256], sq[256];
  float s = 0.f, q = 0.f;
  const float2* pp = (const float2*)part;
  for (int g = tid; g < NG; g += 256) {
    float2 v = pp[(size_t)g * DC + o];
    s += v.x; q += v.y;
  }
  ss[tid] = s; sq[tid] = q;
  __syncthreads();
  for (int w = 128; w > 0; w >>= 1) {
    if (tid < w) { ss[tid] += ss[tid + w]; sq[tid] += sq[tid + w]; }
    __syncthreads();
  }
  if (tid == 0) {
    float mu = ss[0] * kInvCnt;
    float var = sq[0] * kInvCnt - mu * mu;
    var = var < 0.f ? 0.f : var;
    float sc = gam[o] * rsqrtf(var + kEps);
    bn[o] = sc;
    bn[DC + o] = bet[o] - mu * sc;
  }
}

// ---------------------------------------------------------------------------
__global__ void k_final(const float* __restrict__ ymax, const float* __restrict__ ymin,
                        const float* __restrict__ bn2, float* __restrict__ out) {
  __shared__ float tmax[32][33], tmin[32][33];
  int ot = blockIdx.x, pt = blockIdx.y, b = blockIdx.z;
  int tx = threadIdx.x, ty = threadIdx.y;  // 32 x 8
#pragma unroll
  for (int k = 0; k < 4; ++k) {
    int pr = ty + k * 8;
    size_t base = ((size_t)(b * DP) + pt * 32 + pr) * DC + ot * 32 + tx;
    tmax[pr][tx] = ymax[base];
    tmin[pr][tx] = ymin[base];
  }
  __syncthreads();
#pragma unroll
  for (int k = 0; k < 4; ++k) {
    int oc = ty + k * 8;
    int o = ot * 32 + oc;
    float sc = bn2[o], sh = bn2[DC + o];
    float m = (sc >= 0.f) ? tmax[tx][oc] : tmin[tx][oc];
    float v = fmaf(sc, m, sh);
    v = v > 0.f ? v : 0.f;
    out[((size_t)(b * DC) + o) * DP + pt * 32 + tx] = v;
  }
}

// ---------------------------------------------------------------------------
extern "C" void kernel_launch(void* const* d_in, const int* in_sizes, int n_in,
                              void* d_out, int out_size, void* d_ws, size_t ws_size,
                              hipStream_t stream) {
  const float* xyz   = (const float*)d_in[0];
  const float* feats = (const float*)d_in[1];
  const float* rot   = (const float*)d_in[2];
  const float* W1    = (const float*)d_in[3];
  const float* g1    = (const float*)d_in[4];
  const float* b1    = (const float*)d_in[5];
  const float* W2    = (const float*)d_in[6];
  const float* g2    = (const float*)d_in[7];
  const float* b2    = (const float*)d_in[8];
  float* out = (float*)d_out;

  float* ws = (float*)d_ws;
  uint*   ftb_u  = (uint*)(ws + OF_FEATST);
  uint4*  ftb    = (uint4*)(ws + OF_FEATST);
  ushort* W1b    = (ushort*)(ws + OF_W1B);
  ushort* W2b    = (ushort*)(ws + OF_W2B);
  int*    idxp   = (int*)(ws + OF_IDX);
  float*  gxp    = ws + OF_GX;
  float2* partp  = (float2*)(ws + OF_PART);
  float*  ymaxp  = ws + OF_YMAX;
  float*  yminp  = ws + OF_YMIN;
  float*  bn1p   = ws + OF_BN1;
  float*  bn2p   = ws + OF_BN2;
  float*  cntp   = ws + OF_CNT;
  float*  gwp    = ws + OF_GW;
  float*  ggp    = ws + OF_GG;
  float*  cmp    = ws + OF_CM;
  float*  cmzp   = ws + OF_YMAX;  // alias: stats phase finishes before ymax written

  k_transpose_feats<<<dim3(DC / 32, DN / 32, DB), dim3(32, 8), 0, stream>>>(feats, ftb_u);
  k_prep_w1<<<(DC * K1 + 255) / 256, 256, 0, stream>>>(W1, W1b);
  k_prep_w2<<<(DC * K2 + 255) / 256, 256, 0, stream>>>(W2, W2b);
  k_query<<<DBP, 64, 0, stream>>>(xyz, rot, idxp, gxp);

  // ---- bn1 stats via count algebra (no GEMM1 stats pass) ----
  k_zero<<<(ZN + 255) / 256, 256, 0, stream>>>(cntp, ZN);
  k_count<<<DBP * DNS / 1024, 256, 0, stream>>>(idxp, gxp, cntp, gwp, ggp);
  k_xxt<<<dim3(5, 5, 32), 256, 0, stream>>>(feats, cntp, gwp, cmzp);
  k_sumcm<<<(CME + 255) / 256, 256, 0, stream>>>(cmzp, cmp);
  k_bn1<<<DC, 256, 0, stream>>>(cmp, ggp, W1, g1, b1, bn1p);

  // ---- fused GEMM1+bn1+relu+GEMM2 + y2 stats/max/min ----
  k_gemm_full<<<NG, 256, 0, stream>>>(ftb, W1b, W2b, idxp, gxp, bn1p, partp,
                                      ymaxp, yminp);
  k_reduce_bn<<<DC, 256, 0, stream>>>((const float*)partp, g2, b2, bn2p);
  k_final<<<dim3(DC / 32, DP / 32, DB), dim3(32, 8), 0, stream>>>(ymaxp, yminp, bn2p, out);
}

// Round 9
// 182.214 us; speedup vs baseline: 1.4265x; 1.0882x over previous
//
#include <hip/hip_runtime.h>
#include <hip/hip_bf16.h>

#define DB 8
#define DN 1024
#define DP 1024
#define DC 256
#define DNS 32
#define DBP (DB * DP)
#define K1 288   // padded GEMM1 K (256 feats + 3 gx + 29 zeros)
#define K2 256
#define XS 296   // x_lds row stride in bf16 elems (592 B; 148 dwords == 20 mod 32)
#define YS 258   // epilogue y-tile row stride in bf16 (129 dwords == 1 mod 32)
#define ROWS 128 // 4 bp per block (round-5 best config)
#define NG (DBP / 4)
#define NK1 (K1 / 32)  // 9
#define NK2 (K2 / 32)  // 8
#define CME (257 * 259)
#define NZ 64    // K-slices for k_xxt

constexpr float kRadius = 0.05f;
constexpr float kR2 = kRadius * kRadius;
constexpr float kHmin = -0.02f;
constexpr float kHmax = 0.04f;
constexpr float kEps = 1e-5f;
constexpr float kInvCnt = 1.0f / (float)(DB * DP * DNS);

typedef __bf16 bf16x8 __attribute__((ext_vector_type(8)));
typedef float f32x4 __attribute__((ext_vector_type(4)));
static_assert(sizeof(bf16x8) == 16, "bf16x8 must be 16B");

// ---- workspace layout (in floats) ----
constexpr size_t OF_FEATST = 0;                                   // B*N*C bf16
constexpr size_t OF_W1B  = OF_FEATST + (size_t)DB * DN * DC / 2;  // DC*K1 bf16
constexpr size_t OF_W2B  = OF_W1B + (size_t)DC * K1 / 2;          // DC*K2 bf16
constexpr size_t OF_IDX  = OF_W2B + (size_t)DC * K2 / 2;          // BP*NS int32
constexpr size_t OF_GX   = OF_IDX + (size_t)DBP * DNS;            // BP*NS*3
constexpr size_t OF_PART = OF_GX + (size_t)DBP * DNS * 3;         // NG*C*2
constexpr size_t OF_YMAX = OF_PART + (size_t)DBP * DC * 2;        // BP*C
constexpr size_t OF_YMIN = OF_YMAX + (size_t)DBP * DC;            // BP*C
constexpr size_t OF_BN1  = OF_YMIN + (size_t)DBP * DC;            // 512
constexpr size_t OF_BN2  = OF_BN1 + 512;                          // 512
// ---- stats-via-counts scratch ----
constexpr size_t OF_CNT  = OF_BN2 + 512;                          // B*N
constexpr size_t OF_GW   = OF_CNT + (size_t)DB * DN;              // B*3*N
constexpr size_t OF_GG   = OF_GW + (size_t)DB * 3 * DN;           // 16 (use 9)
constexpr size_t OF_CM   = OF_GG + 16;                            // 257*259
constexpr int    ZN      = DB * DN + DB * 3 * DN + 16;
// Cmz slices (NZ x 257*259 = 17MB) alias part+ymax+ymin (33.5MB): stats phase
// completes before k_gemm_full writes them (stream-ordered).

__device__ inline ushort f2b(float x) {
  union { __hip_bfloat16 h; ushort u; } c;
  c.h = __float2bfloat16(x);
  return c.u;
}
__device__ inline float b2f(ushort u) {
  union { uint u; float f; } c;
  c.u = (uint)u << 16;
  return c.f;
}

// ---------------------------------------------------------------------------
// feats (B,C,N) f32 -> featsTb (B,N,C) bf16 via LDS tile transpose
__global__ void k_transpose_feats(const float* __restrict__ f, uint* __restrict__ ftb) {
  __shared__ float t[32][33];
  int ct = blockIdx.x, nt = blockIdx.y, b = blockIdx.z;
  int tx = threadIdx.x, ty = threadIdx.y;  // 32 x 8
#pragma unroll
  for (int k = 0; k < 4; ++k) {
    int c = ct * 32 + ty + k * 8;
    t[ty + k * 8][tx] = f[((size_t)b * DC + c) * DN + nt * 32 + tx];
  }
  __syncthreads();
  int tid = ty * 32 + tx;
  uint* dst = ftb + (size_t)b * DN * (DC / 2);
#pragma unroll
  for (int it = 0; it < 2; ++it) {
    int idx = it * 256 + tid;
    int nl = idx >> 4, cp = idx & 15;
    uint v = (uint)f2b(t[2 * cp][nl]) | ((uint)f2b(t[2 * cp + 1][nl]) << 16);
    dst[(size_t)(nt * 32 + nl) * (DC / 2) + ct * 16 + cp] = v;
  }
}

// W1 (256,259) f32 -> W1b (256,K1) bf16, K permuted: k'=0..255 <- k=3..258,
// k'=256..258 <- k=0..2 (gx), rest zero
__global__ void k_prep_w1(const float* __restrict__ W1, ushort* __restrict__ W1b) {
  int gid = blockIdx.x * 256 + threadIdx.x;
  if (gid >= DC * K1) return;
  int o = gid / K1, kp = gid - o * K1;
  float v = 0.f;
  if (kp < 256) v = W1[o * 259 + 3 + kp];
  else if (kp < 259) v = W1[o * 259 + (kp - 256)];
  W1b[gid] = f2b(v);
}

__global__ void k_prep_w2(const float* __restrict__ W2, ushort* __restrict__ W2b) {
  int gid = blockIdx.x * 256 + threadIdx.x;
  if (gid >= DC * K2) return;
  W2b[gid] = f2b(W2[gid]);
}

// ---------------------------------------------------------------------------
// cylinder query + grouped/rotated xyz. One wave per (b,p).
__global__ void k_query(const float* __restrict__ xyz, const float* __restrict__ rot,
                        int* __restrict__ idxp, float* __restrict__ gxp) {
  int bp = blockIdx.x;
  int b = bp >> 10;
  int lane = threadIdx.x;
  __shared__ int sidx[DNS];
  __shared__ float srot[9], sc[3];
  if (lane < DNS) sidx[lane] = 0;
  if (lane < 9) srot[lane] = rot[(size_t)bp * 9 + lane];
  if (lane < 3) sc[lane] = xyz[(size_t)bp * 3 + lane];
  __syncthreads();
  float r00 = srot[0], r01 = srot[1], r02 = srot[2];
  float r10 = srot[3], r11 = srot[4], r12 = srot[5];
  float r20 = srot[6], r21 = srot[7], r22 = srot[8];
  float cx = sc[0], cy = sc[1], cz = sc[2];
  const float* xb = xyz + (size_t)b * DN * 3;
  int cnt = 0;
  for (int ch = 0; ch < DN / 64 && cnt < DNS; ++ch) {
    int n = ch * 64 + lane;
    float dx = xb[n * 3 + 0] - cx, dy = xb[n * 3 + 1] - cy, dz = xb[n * 3 + 2] - cz;
    float lx = dx * r00 + dy * r10 + dz * r20;
    float ly = dx * r01 + dy * r11 + dz * r21;
    float lz = dx * r02 + dy * r12 + dz * r22;
    bool m = (ly * ly + lz * lz < kR2) && (lx > kHmin) && (lx < kHmax);
    unsigned long long bal = __ballot(m);
    int rank = cnt + __popcll(bal & ((1ull << lane) - 1ull));
    if (m && rank < DNS) sidx[rank] = n;
    cnt += __popcll(bal);
  }
  __syncthreads();
  if (lane < DNS) {
    int j = sidx[lane];
    idxp[(size_t)bp * DNS + lane] = j;
    float gx = (xb[j * 3 + 0] - cx) / kRadius;
    float gy = (xb[j * 3 + 1] - cy) / kRadius;
    float gz = (xb[j * 3 + 2] - cz) / kRadius;
    float* gp = gxp + ((size_t)bp * DNS + lane) * 3;
    gp[0] = gx * r00 + gy * r10 + gz * r20;
    gp[1] = gx * r01 + gy * r11 + gz * r21;
    gp[2] = gx * r02 + gy * r12 + gz * r22;
  }
}

// ---------------------------------------------------------------------------
// zero scratch for the stats pipeline
__global__ void k_zero(float* __restrict__ p, int n) {
  int i = blockIdx.x * 256 + threadIdx.x;
  if (i < n) p[i] = 0.f;
}

// counts + weighted-gx sums per (b, point) via per-block LDS histogram
// (hot j=0 from empty-slot padding serializes in LDS, not L2);
// gx*gx^T 3x3 global sum. 256 blocks x 256 threads x 4 samples each;
// each block covers 1024 consecutive samples = 32 bp = single batch.
__global__ __launch_bounds__(256)
void k_count(const int* __restrict__ idxp, const float* __restrict__ gxp,
             float* __restrict__ cnt, float* __restrict__ gw, float* __restrict__ gg) {
  __shared__ float h0[DN], h1[DN], h2[DN], h3[DN];
  int t = threadIdx.x;
  int b = blockIdx.x >> 5;  // 32 blocks per batch
  for (int i = t; i < DN; i += 256) {
    h0[i] = 0.f; h1[i] = 0.f; h2[i] = 0.f; h3[i] = 0.f;
  }
  __syncthreads();
  float p[6] = {0.f, 0.f, 0.f, 0.f, 0.f, 0.f};
#pragma unroll
  for (int r = 0; r < 4; ++r) {
    int sid = blockIdx.x * 1024 + r * 256 + t;
    int j = idxp[sid];
    const float* g = gxp + (size_t)sid * 3;
    float g0 = g[0], g1 = g[1], g2 = g[2];
    atomicAdd(&h0[j], 1.f);
    atomicAdd(&h1[j], g0);
    atomicAdd(&h2[j], g1);
    atomicAdd(&h3[j], g2);
    p[0] += g0 * g0; p[1] += g0 * g1; p[2] += g0 * g2;
    p[3] += g1 * g1; p[4] += g1 * g2; p[5] += g2 * g2;
  }
  __syncthreads();
  for (int i = t; i < DN; i += 256) {
    float c = h0[i];
    if (c != 0.f) {
      atomicAdd(&cnt[b * DN + i], c);
      atomicAdd(&gw[(b * 3 + 0) * DN + i], h1[i]);
      atomicAdd(&gw[(b * 3 + 1) * DN + i], h2[i]);
      atomicAdd(&gw[(b * 3 + 2) * DN + i], h3[i]);
    }
  }
  __shared__ float sgg[4][6];
#pragma unroll
  for (int v = 0; v < 6; ++v) {
    float s = p[v];
#pragma unroll
    for (int m = 1; m < 64; m <<= 1) s += __shfl_xor(s, m, 64);
    if ((t & 63) == 0) sgg[t >> 6][v] = s;
  }
  __syncthreads();
  if (t < 6) {
    float s = sgg[0][t] + sgg[1][t] + sgg[2][t] + sgg[3][t];
    const int i1[6] = {0, 1, 2, 4, 5, 8};  // (0,0)(0,1)(0,2)(1,1)(1,2)(2,2)
    const int i2[6] = {0, 3, 6, 4, 7, 8};
    atomicAdd(&gg[i1[t]], s);
    if (i2[t] != i1[t]) atomicAdd(&gg[i2[t]], s);
  }
}

// Cmz[z] = F'(257 x K-slice) * P^T: F' rows 0..255 = feats, 256 = ones;
// P cols: k2<256 -> feats*cnt, 256..258 -> gw. grid (5,5,NZ): z = batch*8+slice.
// LDS rows padded to 68 floats (272B = 17x16B) so &As[kk][ty*4] is always
// 16B-aligned -> ds_read_b128 (65-pad forced scalar b32 reads: the round-8 bug).
__global__ __launch_bounds__(256)
void k_xxt(const float* __restrict__ feats, const float* __restrict__ cnt,
           const float* __restrict__ gw, float* __restrict__ Cmz) {
  __shared__ float As[16][68], Bs[16][68];
  int bt = blockIdx.z >> 3;
  int n0 = (blockIdx.z & 7) * 128;
  int r0 = blockIdx.x * 64, c0 = blockIdx.y * 64;
  int tid = threadIdx.x;
  int ty = tid >> 4, tx = tid & 15;
  int li = tid >> 2, lq = tid & 3;
  const float* fb = feats + (size_t)bt * DC * DN;
  const float* cb = cnt + (size_t)bt * DN;
  const float* gb = gw + (size_t)bt * 3 * DN;
  float acc[4][4];
#pragma unroll
  for (int u = 0; u < 4; ++u)
#pragma unroll
    for (int v = 0; v < 4; ++v) acc[u][v] = 0.f;

  for (int nc = n0; nc < n0 + 128; nc += 16) {
    __syncthreads();
    {
      int k1 = r0 + li;
      float4 av = make_float4(0.f, 0.f, 0.f, 0.f);
      if (k1 < 256) av = *(const float4*)(fb + (size_t)k1 * DN + nc + lq * 4);
      else if (k1 == 256) av = make_float4(1.f, 1.f, 1.f, 1.f);
      As[lq * 4 + 0][li] = av.x; As[lq * 4 + 1][li] = av.y;
      As[lq * 4 + 2][li] = av.z; As[lq * 4 + 3][li] = av.w;
      int k2 = c0 + li;
      float4 bv = make_float4(0.f, 0.f, 0.f, 0.f);
      if (k2 < 256) {
        float4 f = *(const float4*)(fb + (size_t)k2 * DN + nc + lq * 4);
        float4 c4 = *(const float4*)(cb + nc + lq * 4);
        bv = make_float4(f.x * c4.x, f.y * c4.y, f.z * c4.z, f.w * c4.w);
      } else if (k2 < 259) {
        bv = *(const float4*)(gb + (size_t)(k2 - 256) * DN + nc + lq * 4);
      }
      Bs[lq * 4 + 0][li] = bv.x; Bs[lq * 4 + 1][li] = bv.y;
      Bs[lq * 4 + 2][li] = bv.z; Bs[lq * 4 + 3][li] = bv.w;
    }
    __syncthreads();
#pragma unroll
    for (int kk = 0; kk < 16; ++kk) {
      float4 a4 = *(const float4*)&As[kk][ty * 4];
      float4 b4 = *(const float4*)&Bs[kk][tx * 4];
      float a[4] = {a4.x, a4.y, a4.z, a4.w};
      float bb[4] = {b4.x, b4.y, b4.z, b4.w};
#pragma unroll
      for (int u = 0; u < 4; ++u)
#pragma unroll
        for (int v = 0; v < 4; ++v) acc[u][v] = fmaf(a[u], bb[v], acc[u][v]);
    }
  }
  float* dst = Cmz + (size_t)blockIdx.z * CME;
#pragma unroll
  for (int u = 0; u < 4; ++u) {
    int k1 = r0 + ty * 4 + u;
    if (k1 > 256) continue;
#pragma unroll
    for (int v = 0; v < 4; ++v) {
      int k2 = c0 + tx * 4 + v;
      if (k2 < 259) dst[(size_t)k1 * 259 + k2] = acc[u][v];
    }
  }
}

// fold the NZ Cmz slices -> Cm
__global__ void k_sumcm(const float* __restrict__ Cmz, float* __restrict__ Cm) {
  int e = blockIdx.x * 256 + threadIdx.x;
  if (e >= CME) return;
  float s = 0.f;
  for (int z = 0; z < NZ; ++z) s += Cmz[(size_t)z * CME + e];
  Cm[e] = s;
}

// per-channel bn1 scale/shift from C, gg: mu = w.sumx/N, Ey2 = w^T M w / N
__global__ __launch_bounds__(256)
void k_bn1(const float* __restrict__ Cm, const float* __restrict__ gg,
           const float* __restrict__ W1, const float* __restrict__ gam,
           const float* __restrict__ bet, float* __restrict__ bn) {
  int o = blockIdx.x, t = threadIdx.x;
  __shared__ float wv[259];
  __shared__ float rq[256], rs[256];
  for (int j = t; j < 259; j += 256)
    wv[j] = (j < 256) ? W1[o * 259 + 3 + j] : W1[o * 259 + (j - 256)];
  __syncthreads();
  float qp = 0.f, sp = 0.f;
  for (int j = t; j < 259; j += 256) {
    float u = 0.f;
    for (int i = 0; i < 256; ++i) u = fmaf(wv[i], Cm[(size_t)i * 259 + j], u);
#pragma unroll
    for (int c = 0; c < 3; ++c) {
      float m = (j < 256) ? Cm[(size_t)j * 259 + 256 + c] : gg[c * 3 + (j - 256)];
      u = fmaf(wv[256 + c], m, u);
    }
    qp = fmaf(wv[j], u, qp);
    sp = fmaf(wv[j], Cm[(size_t)256 * 259 + j], sp);
  }
  rq[t] = qp; rs[t] = sp;
  __syncthreads();
  for (int w = 128; w > 0; w >>= 1) {
    if (t < w) { rq[t] += rq[t + w]; rs[t] += rs[t + w]; }
    __syncthreads();
  }
  if (t == 0) {
    float mu = rs[0] * kInvCnt;
    float var = rq[0] * kInvCnt - mu * mu;
    var = var < 0.f ? 0.f : var;
    float sc = gam[o] * rsqrtf(var + kEps);
    bn[o] = sc;
    bn[DC + o] = bet[o] - mu * sc;
  }
}

// ---------------------------------------------------------------------------
// MFMA GEMM over 4 bp per block (128 sample rows), 16x16x32 bf16 — round-5 FULL.
// 256 threads = 4 waves; wave w owns o-range w*64 (4 o-tiles of 16), 8 s-tiles.
// D layout: col = lane&15 (=s), row = (lane>>4)*4 + reg (=o).
__global__ __launch_bounds__(256, 2)
void k_gemm_full(const uint4* __restrict__ ftb, const ushort* __restrict__ W1b,
                 const ushort* __restrict__ W2b, const int* __restrict__ idxp,
                 const float* __restrict__ gxp, const float* __restrict__ bn1,
                 float2* __restrict__ part, float* __restrict__ ymax,
                 float* __restrict__ ymin) {
  __shared__ ushort x_lds[ROWS * XS];   // 75776 B; also holds 128x258 y tile
  __shared__ float bn_lds[2 * DC];

  const int grp = blockIdx.x;           // 0..NG-1
  const int bp0 = grp * 4;
  const int b = bp0 >> 10;
  const int tid = threadIdx.x;
  const int lane = tid & 63;
  const int wv = tid >> 6;
  const int l15 = lane & 15;
  const int l4 = lane >> 4;

  for (int i = tid; i < 2 * DC; i += 256) bn_lds[i] = bn1[i];

  // ---- gather feats: 8 threads/row, 128-B coalesced segments ----
  {
    int q = tid & 7;
#pragma unroll
    for (int rep = 0; rep < 4; ++rep) {
      int s = (tid >> 3) + rep * 32;
      int j = idxp[(size_t)bp0 * DNS + s];
      const uint4* src = ftb + (size_t)(b * DN + j) * (DC / 8);
      uint4* dst = (uint4*)(x_lds + (size_t)s * XS);
#pragma unroll
      for (int k = 0; k < 4; ++k) dst[q + 8 * k] = src[q + 8 * k];
    }
  }
  // ---- gx channels at k=256..258, zeros to 287 ----
  if (tid < ROWS) {
    const float* g = gxp + ((size_t)bp0 * DNS + tid) * 3;
    uint a0 = (uint)f2b(g[0]) | ((uint)f2b(g[1]) << 16);
    uint a1 = (uint)f2b(g[2]);
    uint4* drow = (uint4*)(x_lds + (size_t)tid * XS + 256);
    drow[0] = make_uint4(a0, a1, 0u, 0u);
    drow[1] = make_uint4(0u, 0u, 0u, 0u);
    drow[2] = make_uint4(0u, 0u, 0u, 0u);
    drow[3] = make_uint4(0u, 0u, 0u, 0u);
  }
  __syncthreads();

  f32x4 acc[4][8];
#pragma unroll
  for (int t = 0; t < 4; ++t)
#pragma unroll
    for (int st = 0; st < 8; ++st)
#pragma unroll
      for (int r = 0; r < 4; ++r) acc[t][st][r] = 0.f;

  const int o0 = wv * 64;
  const ushort* xbase = x_lds + (size_t)l15 * XS + l4 * 8;

  // ---- GEMM1: K = 288, 9 K-steps of 32; A prefetched one step ahead ----
  {
    const ushort* wrow[4];
#pragma unroll
    for (int t = 0; t < 4; ++t)
      wrow[t] = W1b + (size_t)(o0 + t * 16 + l15) * K1 + l4 * 8;
    bf16x8 aw[4];
#pragma unroll
    for (int t = 0; t < 4; ++t) aw[t] = *(const bf16x8*)(wrow[t]);
#pragma unroll
    for (int ks = 0; ks < NK1; ++ks) {
      bf16x8 bx[8];
#pragma unroll
      for (int st = 0; st < 8; ++st)
        bx[st] = *(const bf16x8*)(xbase + (size_t)st * 16 * XS + ks * 32);
      bf16x8 an[4];
      if (ks + 1 < NK1) {
#pragma unroll
        for (int t = 0; t < 4; ++t)
          an[t] = *(const bf16x8*)(wrow[t] + (ks + 1) * 32);
      }
#pragma unroll
      for (int st = 0; st < 8; ++st)
#pragma unroll
        for (int t = 0; t < 4; ++t)
          acc[t][st] = __builtin_amdgcn_mfma_f32_16x16x32_bf16(aw[t], bx[st],
                                                               acc[t][st], 0, 0, 0);
      if (ks + 1 < NK1) {
#pragma unroll
        for (int t = 0; t < 4; ++t) aw[t] = an[t];
      }
    }
  }

  // ---- bn1 + relu -> x2 (bf16) back into x_lds[s][o] (stride XS) ----
  __syncthreads();  // all GEMM1 LDS reads complete before overwrite
#pragma unroll
  for (int t = 0; t < 4; ++t) {
    int ob = o0 + t * 16 + l4 * 4;
    float sc0 = bn_lds[ob + 0], sh0 = bn_lds[DC + ob + 0];
    float sc1 = bn_lds[ob + 1], sh1 = bn_lds[DC + ob + 1];
    float sc2 = bn_lds[ob + 2], sh2 = bn_lds[DC + ob + 2];
    float sc3 = bn_lds[ob + 3], sh3 = bn_lds[DC + ob + 3];
#pragma unroll
    for (int st = 0; st < 8; ++st) {
      float v0 = fmaxf(fmaf(acc[t][st][0], sc0, sh0), 0.f);
      float v1 = fmaxf(fmaf(acc[t][st][1], sc1, sh1), 0.f);
      float v2 = fmaxf(fmaf(acc[t][st][2], sc2, sh2), 0.f);
      float v3 = fmaxf(fmaf(acc[t][st][3], sc3, sh3), 0.f);
      uint2 pk = make_uint2((uint)f2b(v0) | ((uint)f2b(v1) << 16),
                            (uint)f2b(v2) | ((uint)f2b(v3) << 16));
      int s = st * 16 + l15;
      *(uint2*)(x_lds + (size_t)s * XS + ob) = pk;
      acc[t][st][0] = 0.f; acc[t][st][1] = 0.f;
      acc[t][st][2] = 0.f; acc[t][st][3] = 0.f;
    }
  }
  __syncthreads();

  // ---- GEMM2: K = 256, 8 K-steps ----
  {
    const ushort* wrow[4];
#pragma unroll
    for (int t = 0; t < 4; ++t)
      wrow[t] = W2b + (size_t)(o0 + t * 16 + l15) * K2 + l4 * 8;
    bf16x8 aw[4];
#pragma unroll
    for (int t = 0; t < 4; ++t) aw[t] = *(const bf16x8*)(wrow[t]);
#pragma unroll
    for (int ks = 0; ks < NK2; ++ks) {
      bf16x8 bx[8];
#pragma unroll
      for (int st = 0; st < 8; ++st)
        bx[st] = *(const bf16x8*)(xbase + (size_t)st * 16 * XS + ks * 32);
      bf16x8 an[4];
      if (ks + 1 < NK2) {
#pragma unroll
        for (int t = 0; t < 4; ++t)
          an[t] = *(const bf16x8*)(wrow[t] + (ks + 1) * 32);
      }
#pragma unroll
      for (int st = 0; st < 8; ++st)
#pragma unroll
        for (int t = 0; t < 4; ++t)
          acc[t][st] = __builtin_amdgcn_mfma_f32_16x16x32_bf16(aw[t], bx[st],
                                                               acc[t][st], 0, 0, 0);
      if (ks + 1 < NK2) {
#pragma unroll
        for (int t = 0; t < 4; ++t) aw[t] = an[t];
      }
    }
  }

  // ---- y2 -> bf16 [s][o] tile, then per-o column stats + per-bp max/min ----
  __syncthreads();
#pragma unroll
  for (int t = 0; t < 4; ++t) {
    int ob = o0 + t * 16 + l4 * 4;
#pragma unroll
    for (int st = 0; st < 8; ++st) {
      uint2 pk = make_uint2(
          (uint)f2b(acc[t][st][0]) | ((uint)f2b(acc[t][st][1]) << 16),
          (uint)f2b(acc[t][st][2]) | ((uint)f2b(acc[t][st][3]) << 16));
      int s = st * 16 + l15;
      *(uint2*)(x_lds + (size_t)s * YS + ob) = pk;
    }
  }
  __syncthreads();
  {
    const ushort* col = x_lds + tid;  // o = tid
    float s = 0.f, q = 0.f;
#pragma unroll
    for (int p = 0; p < 4; ++p) {
      float mx = -3.4e38f, mn = 3.4e38f;
#pragma unroll 8
      for (int i = 0; i < DNS; ++i) {
        float v = b2f(col[(size_t)(p * DNS + i) * YS]);
        s += v; q += v * v;
        mx = fmaxf(mx, v); mn = fminf(mn, v);
      }
      ymax[(size_t)(bp0 + p) * DC + tid] = mx;
      ymin[(size_t)(bp0 + p) * DC + tid] = mn;
    }
    part[(size_t)grp * DC + tid] = make_float2(s, q);
  }
}

// ---------------------------------------------------------------------------
__global__ void k_reduce_bn(const float* __restrict__ part, const float* __restrict__ gam,
                            const float* __restrict__ bet, float* __restrict__ bn) {
  int o = blockIdx.x, tid = threadIdx.x;
  __shared__ float ss[256], sq[256];
  float s = 0.f, q = 0.f;
  const float2* pp = (const float2*)part;
  for (int g = tid; g < NG; g += 256) {
    float2 v = pp[(size_t)g * DC + o];
    s += v.x; q += v.y;
  }
  ss[tid] = s; sq[tid] = q;
  __syncthreads();
  for (int w = 128; w > 0; w >>= 1) {
    if (tid < w) { ss[tid] += ss[tid + w]; sq[tid] += sq[tid + w]; }
    __syncthreads();
  }
  if (tid == 0) {
    float mu = ss[0] * kInvCnt;
    float var = sq[0] * kInvCnt - mu * mu;
    var = var < 0.f ? 0.f : var;
    float sc = gam[o] * rsqrtf(var + kEps);
    bn[o] = sc;
    bn[DC + o] = bet[o] - mu * sc;
  }
}

// ---------------------------------------------------------------------------
__global__ void k_final(const float* __restrict__ ymax, const float* __restrict__ ymin,
                        const float* __restrict__ bn2, float* __restrict__ out) {
  __shared__ float tmax[32][33], tmin[32][33];
  int ot = blockIdx.x, pt = blockIdx.y, b = blockIdx.z;
  int tx = threadIdx.x, ty = threadIdx.y;  // 32 x 8
#pragma unroll
  for (int k = 0; k < 4; ++k) {
    int pr = ty + k * 8;
    size_t base = ((size_t)(b * DP) + pt * 32 + pr) * DC + ot * 32 + tx;
    tmax[pr][tx] = ymax[base];
    tmin[pr][tx] = ymin[base];
  }
  __syncthreads();
#pragma unroll
  for (int k = 0; k < 4; ++k) {
    int oc = ty + k * 8;
    int o = ot * 32 + oc;
    float sc = bn2[o], sh = bn2[DC + o];
    float m = (sc >= 0.f) ? tmax[tx][oc] : tmin[tx][oc];
    float v = fmaf(sc, m, sh);
    v = v > 0.f ? v : 0.f;
    out[((size_t)(b * DC) + o) * DP + pt * 32 + tx] = v;
  }
}

// ---------------------------------------------------------------------------
extern "C" void kernel_launch(void* const* d_in, const int* in_sizes, int n_in,
                              void* d_out, int out_size, void* d_ws, size_t ws_size,
                              hipStream_t stream) {
  const float* xyz   = (const float*)d_in[0];
  const float* feats = (const float*)d_in[1];
  const float* rot   = (const float*)d_in[2];
  const float* W1    = (const float*)d_in[3];
  const float* g1    = (const float*)d_in[4];
  const float* b1    = (const float*)d_in[5];
  const float* W2    = (const float*)d_in[6];
  const float* g2    = (const float*)d_in[7];
  const float* b2    = (const float*)d_in[8];
  float* out = (float*)d_out;

  float* ws = (float*)d_ws;
  uint*   ftb_u  = (uint*)(ws + OF_FEATST);
  uint4*  ftb    = (uint4*)(ws + OF_FEATST);
  ushort* W1b    = (ushort*)(ws + OF_W1B);
  ushort* W2b    = (ushort*)(ws + OF_W2B);
  int*    idxp   = (int*)(ws + OF_IDX);
  float*  gxp    = ws + OF_GX;
  float2* partp  = (float2*)(ws + OF_PART);
  float*  ymaxp  = ws + OF_YMAX;
  float*  yminp  = ws + OF_YMIN;
  float*  bn1p   = ws + OF_BN1;
  float*  bn2p   = ws + OF_BN2;
  float*  cntp   = ws + OF_CNT;
  float*  gwp    = ws + OF_GW;
  float*  ggp    = ws + OF_GG;
  float*  cmp    = ws + OF_CM;
  float*  cmzp   = ws + OF_PART;  // alias part+ymax+ymin (33.5MB >= NZ*CME*4);
                                  // stats phase finishes before they are written

  k_transpose_feats<<<dim3(DC / 32, DN / 32, DB), dim3(32, 8), 0, stream>>>(feats, ftb_u);
  k_prep_w1<<<(DC * K1 + 255) / 256, 256, 0, stream>>>(W1, W1b);
  k_prep_w2<<<(DC * K2 + 255) / 256, 256, 0, stream>>>(W2, W2b);
  k_query<<<DBP, 64, 0, stream>>>(xyz, rot, idxp, gxp);

  // ---- bn1 stats via count algebra (no GEMM1 stats pass) ----
  k_zero<<<(ZN + 255) / 256, 256, 0, stream>>>(cntp, ZN);
  k_count<<<DBP * DNS / 1024, 256, 0, stream>>>(idxp, gxp, cntp, gwp, ggp);
  k_xxt<<<dim3(5, 5, NZ), 256, 0, stream>>>(feats, cntp, gwp, cmzp);
  k_sumcm<<<(CME + 255) / 256, 256, 0, stream>>>(cmzp, cmp);
  k_bn1<<<DC, 256, 0, stream>>>(cmp, ggp, W1, g1, b1, bn1p);

  // ---- fused GEMM1+bn1+relu+GEMM2 + y2 stats/max/min ----
  k_gemm_full<<<NG, 256, 0, stream>>>(ftb, W1b, W2b, idxp, gxp, bn1p, partp,
                                      ymaxp, yminp);
  k_reduce_bn<<<DC, 256, 0, stream>>>((const float*)partp, g2, b2, bn2p);
  k_final<<<dim3(DC / 32, DP / 32, DB), dim3(32, 8), 0, stream>>>(ymaxp, yminp, bn2p, out);
}